// Round 1
// baseline (1783.896 us; speedup 1.0000x reference)
//
#include <hip/hip_runtime.h>
#include <stdint.h>

#define T_STEPS 300
#define T4 75

// ---- scan (psp + spike) constants ----
// d = exp(-1), c = e, cr = -2*theta*e, theta = 10
__device__ __forceinline__ void scan_step(float x, float& pp, float& pq,
                                          float& rp, float& rq, float& s_out) {
    const float D  = 0.36787944117144233f;
    const float C  = 2.7182818284590452f;
    const float CR = -54.365636569180904f;
    const float TH = 10.0f;
    pq = D * (pq + pp);      // psp state (q uses old p -> eps[0]=0)
    pp = D * pp + x;
    float u = C * pq;
    rq = D * (rq + rp);      // refractory state (q uses old p)
    float s = (u + CR * rq >= TH) ? 1.0f : 0.0f;
    rp = D * rp + s;
    s_out = s;
}

__global__ __launch_bounds__(256) void k_scan_u8(const float* __restrict__ z,
                                                 uint8_t* __restrict__ s, int N) {
    int n = blockIdx.x * 256 + threadIdx.x;
    if (n >= N) return;
    const float4* zp = reinterpret_cast<const float4*>(z + (size_t)n * T_STEPS);
    uint8_t* sp = s + (size_t)n * T_STEPS;
    float pp = 0.f, pq = 0.f, rp = 0.f, rq = 0.f;
    for (int it = 0; it < T4; ++it) {
        float4 v = zp[it];
        float s0, s1, s2, s3;
        scan_step(v.x, pp, pq, rp, rq, s0);
        scan_step(v.y, pp, pq, rp, rq, s1);
        scan_step(v.z, pp, pq, rp, rq, s2);
        scan_step(v.w, pp, pq, rp, rq, s3);
        uint32_t pack = (uint32_t)s0 | ((uint32_t)s1 << 8) |
                        ((uint32_t)s2 << 16) | ((uint32_t)s3 << 24);
        *reinterpret_cast<uint32_t*>(sp + it * 4) = pack;
    }
}

__global__ __launch_bounds__(256) void k_scan_f32(const float* __restrict__ z,
                                                  float* __restrict__ s, int N) {
    int n = blockIdx.x * blockDim.x + threadIdx.x;
    if (n >= N) return;
    const float4* zp = reinterpret_cast<const float4*>(z + (size_t)n * T_STEPS);
    float* sp = s + (size_t)n * T_STEPS;
    float pp = 0.f, pq = 0.f, rp = 0.f, rq = 0.f;
    for (int it = 0; it < T4; ++it) {
        float4 v = zp[it];
        float4 o;
        scan_step(v.x, pp, pq, rp, rq, o.x);
        scan_step(v.y, pp, pq, rp, rq, o.y);
        scan_step(v.z, pp, pq, rp, rq, o.z);
        scan_step(v.w, pp, pq, rp, rq, o.w);
        *reinterpret_cast<float4*>(sp + it * 4) = o;
    }
}

// ---- SP0 spatial: 4x4 sum-pool * 11 on raw input, t-vectorized ----
__global__ __launch_bounds__(256) void k_pool4(const float* __restrict__ in,
                                               float* __restrict__ z) {
    int idx = blockIdx.x * 256 + threadIdx.x;   // 16384 * 75
    int t4 = idx % T4;
    int n  = idx / T4;                // (b*2+c)*1024 + y*32 + x
    int x = n & 31, y = (n >> 5) & 31, bc = n >> 10;
    const float* base = in + ((size_t)bc * 16384 + (size_t)(4 * y) * 128 + 4 * x) * T_STEPS + 4 * t4;
    float4 acc = {0.f, 0.f, 0.f, 0.f};
#pragma unroll
    for (int i = 0; i < 4; ++i)
#pragma unroll
        for (int j = 0; j < 4; ++j) {
            float4 v = *reinterpret_cast<const float4*>(base + ((size_t)i * 128 + j) * T_STEPS);
            acc.x += v.x; acc.y += v.y; acc.z += v.z; acc.w += v.w;
        }
    float4 o = {11.f * acc.x, 11.f * acc.y, 11.f * acc.z, 11.f * acc.w};
    *reinterpret_cast<float4*>(z + (size_t)n * T_STEPS + 4 * t4) = o;
}

// ---- generic 2x2 sum-pool * 11 on u8 spikes ----
__global__ __launch_bounds__(256) void k_pool2(const uint8_t* __restrict__ s,
                                               float* __restrict__ z, int HW) {
    int idx = blockIdx.x * 256 + threadIdx.x;
    int t4 = idx % T4;
    int n  = idx / T4;
    int x = n % HW;
    int y = (n / HW) % HW;
    int bc = n / (HW * HW);
    int W2d = HW * 2;
    const uint8_t* base = s + ((size_t)bc * W2d * W2d + (size_t)(2 * y) * W2d + 2 * x) * T_STEPS + 4 * t4;
    uint32_t v00 = *reinterpret_cast<const uint32_t*>(base);
    uint32_t v01 = *reinterpret_cast<const uint32_t*>(base + T_STEPS);
    uint32_t v10 = *reinterpret_cast<const uint32_t*>(base + (size_t)W2d * T_STEPS);
    uint32_t v11 = *reinterpret_cast<const uint32_t*>(base + (size_t)(W2d + 1) * T_STEPS);
    float4 o;
    o.x = 11.f * (float)((v00 & 0xffu) + (v01 & 0xffu) + (v10 & 0xffu) + (v11 & 0xffu));
    o.y = 11.f * (float)(((v00 >> 8) & 0xffu) + ((v01 >> 8) & 0xffu) + ((v10 >> 8) & 0xffu) + ((v11 >> 8) & 0xffu));
    o.z = 11.f * (float)(((v00 >> 16) & 0xffu) + ((v01 >> 16) & 0xffu) + ((v10 >> 16) & 0xffu) + ((v11 >> 16) & 0xffu));
    o.w = 11.f * (float)((v00 >> 24) + (v01 >> 24) + (v10 >> 24) + (v11 >> 24));
    *reinterpret_cast<float4*>(z + (size_t)n * T_STEPS + 4 * t4) = o;
}

// ---- SC1: 5x5 conv, 2->16, 32x32, pad 2, over 2 b's per pass ----
__global__ __launch_bounds__(256) void k_conv1(const uint8_t* __restrict__ s0,
                                               const float* __restrict__ W1,
                                               float* __restrict__ z, int b0) {
    int idx = blockIdx.x * 256 + threadIdx.x;   // 2*16*1024*75
    int t4 = idx % T4;
    int r  = idx / T4;            // ((bb*16+o)*32+y)*32+x
    int x = r & 31, y = (r >> 5) & 31, o = (r >> 10) & 15, bb = r >> 14;
    int b = b0 + bb;
    float a0 = 0.f, a1 = 0.f, a2 = 0.f, a3 = 0.f;
#pragma unroll
    for (int c = 0; c < 2; ++c) {
        float w[25];
#pragma unroll
        for (int j = 0; j < 25; ++j) w[j] = W1[(o * 2 + c) * 25 + j];
        const uint8_t* cbase = s0 + ((size_t)(b * 2 + c) * 1024) * T_STEPS + 4 * t4;
#pragma unroll
        for (int ky = 0; ky < 5; ++ky) {
            int yy = y + ky - 2;
            if (yy < 0 || yy >= 32) continue;
#pragma unroll
            for (int kx = 0; kx < 5; ++kx) {
                int xx = x + kx - 2;
                if (xx < 0 || xx >= 32) continue;
                uint32_t v = *reinterpret_cast<const uint32_t*>(cbase + (size_t)(yy * 32 + xx) * T_STEPS);
                float wv = w[ky * 5 + kx];
                a0 = fmaf(wv, (float)(v & 0xffu), a0);
                a1 = fmaf(wv, (float)((v >> 8) & 0xffu), a1);
                a2 = fmaf(wv, (float)((v >> 16) & 0xffu), a2);
                a3 = fmaf(wv, (float)(v >> 24), a3);
            }
        }
    }
    *reinterpret_cast<float4*>(z + (size_t)r * T_STEPS + 4 * t4) = make_float4(a0, a1, a2, a3);
}

// ---- SC2: 3x3 conv, 16->32, 16x16, pad 1, over 4 b's per pass ----
__global__ __launch_bounds__(256) void k_conv2(const uint8_t* __restrict__ s2,
                                               const float* __restrict__ W2,
                                               float* __restrict__ z, int b0) {
    int idx = blockIdx.x * 256 + threadIdx.x;   // 4*32*256*75
    int t4 = idx % T4;
    int r  = idx / T4;            // ((bb*32+o)*16+y)*16+x
    int x = r & 15, y = (r >> 4) & 15, o = (r >> 8) & 31, bb = r >> 13;
    int b = b0 + bb;
    float a0 = 0.f, a1 = 0.f, a2 = 0.f, a3 = 0.f;
#pragma unroll
    for (int cc = 0; cc < 4; ++cc) {          // 4 channels per chunk
        float w[36];
#pragma unroll
        for (int j = 0; j < 36; ++j) w[j] = W2[o * 144 + cc * 36 + j];
#pragma unroll
        for (int ci = 0; ci < 4; ++ci) {
            int c = cc * 4 + ci;
            const uint8_t* cbase = s2 + ((size_t)(b * 16 + c) * 256) * T_STEPS + 4 * t4;
#pragma unroll
            for (int ky = 0; ky < 3; ++ky) {
                int yy = y + ky - 1;
                if (yy < 0 || yy >= 16) continue;
#pragma unroll
                for (int kx = 0; kx < 3; ++kx) {
                    int xx = x + kx - 1;
                    if (xx < 0 || xx >= 16) continue;
                    uint32_t v = *reinterpret_cast<const uint32_t*>(cbase + (size_t)(yy * 16 + xx) * T_STEPS);
                    float wv = w[ci * 9 + ky * 3 + kx];
                    a0 = fmaf(wv, (float)(v & 0xffu), a0);
                    a1 = fmaf(wv, (float)((v >> 8) & 0xffu), a1);
                    a2 = fmaf(wv, (float)((v >> 16) & 0xffu), a2);
                    a3 = fmaf(wv, (float)(v >> 24), a3);
                }
            }
        }
    }
    *reinterpret_cast<float4*>(z + (size_t)r * T_STEPS + 4 * t4) = make_float4(a0, a1, a2, a3);
}

// ---- SF1: 2048 -> 512 FC (spikes stored as float) ----
__global__ __launch_bounds__(256) void k_fc1(const float* __restrict__ s4,
                                             const float* __restrict__ Wf1,
                                             float* __restrict__ z) {
    int idx = blockIdx.x * 256 + threadIdx.x;   // 512*8*75
    int t4 = idx % T4;
    int r  = idx / T4;            // o*8 + b  (o wave-uniform -> broadcast weight loads)
    int b = r & 7, o = r >> 3;
    const float* sp = s4 + (size_t)b * 2048 * T_STEPS + 4 * t4;
    const float* wp = Wf1 + (size_t)o * 2048;
    float a0 = 0.f, a1 = 0.f, a2 = 0.f, a3 = 0.f;
#pragma unroll 2
    for (int k = 0; k < 2048; k += 4) {
        float4 wv = *reinterpret_cast<const float4*>(wp + k);
        float4 v0 = *reinterpret_cast<const float4*>(sp + (size_t)(k + 0) * T_STEPS);
        float4 v1 = *reinterpret_cast<const float4*>(sp + (size_t)(k + 1) * T_STEPS);
        float4 v2 = *reinterpret_cast<const float4*>(sp + (size_t)(k + 2) * T_STEPS);
        float4 v3 = *reinterpret_cast<const float4*>(sp + (size_t)(k + 3) * T_STEPS);
        a0 = fmaf(wv.x, v0.x, a0); a1 = fmaf(wv.x, v0.y, a1); a2 = fmaf(wv.x, v0.z, a2); a3 = fmaf(wv.x, v0.w, a3);
        a0 = fmaf(wv.y, v1.x, a0); a1 = fmaf(wv.y, v1.y, a1); a2 = fmaf(wv.y, v1.z, a2); a3 = fmaf(wv.y, v1.w, a3);
        a0 = fmaf(wv.z, v2.x, a0); a1 = fmaf(wv.z, v2.y, a1); a2 = fmaf(wv.z, v2.z, a2); a3 = fmaf(wv.z, v2.w, a3);
        a0 = fmaf(wv.w, v3.x, a0); a1 = fmaf(wv.w, v3.y, a1); a2 = fmaf(wv.w, v3.z, a2); a3 = fmaf(wv.w, v3.w, a3);
    }
    *reinterpret_cast<float4*>(z + (size_t)(b * 512 + o) * T_STEPS + 4 * t4) = make_float4(a0, a1, a2, a3);
}

// ---- SF2: 512 -> 11 FC ----
__global__ __launch_bounds__(256) void k_fc2(const float* __restrict__ s5,
                                             const float* __restrict__ Wf2,
                                             float* __restrict__ z) {
    int idx = blockIdx.x * 256 + threadIdx.x;   // 11*8*75 = 6600
    if (idx >= 6600) return;
    int t4 = idx % T4;
    int r  = idx / T4;            // o*8 + b
    int b = r & 7, o = r >> 3;
    const float* sp = s5 + (size_t)b * 512 * T_STEPS + 4 * t4;
    const float* wp = Wf2 + (size_t)o * 512;
    float a0 = 0.f, a1 = 0.f, a2 = 0.f, a3 = 0.f;
#pragma unroll 2
    for (int k = 0; k < 512; k += 4) {
        float4 wv = *reinterpret_cast<const float4*>(wp + k);
        float4 v0 = *reinterpret_cast<const float4*>(sp + (size_t)(k + 0) * T_STEPS);
        float4 v1 = *reinterpret_cast<const float4*>(sp + (size_t)(k + 1) * T_STEPS);
        float4 v2 = *reinterpret_cast<const float4*>(sp + (size_t)(k + 2) * T_STEPS);
        float4 v3 = *reinterpret_cast<const float4*>(sp + (size_t)(k + 3) * T_STEPS);
        a0 = fmaf(wv.x, v0.x, a0); a1 = fmaf(wv.x, v0.y, a1); a2 = fmaf(wv.x, v0.z, a2); a3 = fmaf(wv.x, v0.w, a3);
        a0 = fmaf(wv.y, v1.x, a0); a1 = fmaf(wv.y, v1.y, a1); a2 = fmaf(wv.y, v1.z, a2); a3 = fmaf(wv.y, v1.w, a3);
        a0 = fmaf(wv.z, v2.x, a0); a1 = fmaf(wv.z, v2.y, a1); a2 = fmaf(wv.z, v2.z, a2); a3 = fmaf(wv.z, v2.w, a3);
        a0 = fmaf(wv.w, v3.x, a0); a1 = fmaf(wv.w, v3.y, a1); a2 = fmaf(wv.w, v3.z, a2); a3 = fmaf(wv.w, v3.w, a3);
    }
    *reinterpret_cast<float4*>(z + (size_t)(b * 11 + o) * T_STEPS + 4 * t4) = make_float4(a0, a1, a2, a3);
}

__global__ void k_zero(float* out, int n) {
    int i = blockIdx.x * 256 + threadIdx.x;
    if (i < n) out[i] = 0.f;
}

extern "C" void kernel_launch(void* const* d_in, const int* in_sizes, int n_in,
                              void* d_out, int out_size, void* d_ws, size_t ws_size,
                              hipStream_t stream) {
    const float* s_in = (const float*)d_in[0];
    const float* W1   = (const float*)d_in[1];
    const float* W2   = (const float*)d_in[2];
    const float* Wf1  = (const float*)d_in[3];
    const float* Wf2  = (const float*)d_in[4];
    float* out = (float*)d_out;

    // workspace layout (bytes)
    const size_t OFF_Z  = 0;               // 9,830,400 floats = 39,321,600 B (reused)
    const size_t OFF_S0 = 39321600;        // u8,  4,915,200
    const size_t OFF_S1 = 44236800;        // u8, 39,321,600
    const size_t OFF_S2 = 83558400;        // u8,  9,830,400
    const size_t OFF_S3 = 93388800;        // u8, 19,660,800
    const size_t OFF_S4 = 113049600;       // f32, 19,660,800
    const size_t OFF_S5 = 132710400;       // f32,  4,915,200
    const size_t NEEDED = 137625600;

    if (ws_size < NEEDED) {   // graceful failure path (deterministic)
        k_zero<<<(26400 + 255) / 256, 256, 0, stream>>>(out, 26400);
        return;
    }

    char* ws = (char*)d_ws;
    float*   z  = (float*)(ws + OFF_Z);
    uint8_t* s0 = (uint8_t*)(ws + OFF_S0);
    uint8_t* s1 = (uint8_t*)(ws + OFF_S1);
    uint8_t* s2 = (uint8_t*)(ws + OFF_S2);
    uint8_t* s3 = (uint8_t*)(ws + OFF_S3);
    float*   s4 = (float*)(ws + OFF_S4);
    float*   s5 = (float*)(ws + OFF_S5);

    // SP0: pool4 + scan
    k_pool4<<<4800, 256, 0, stream>>>(s_in, z);
    k_scan_u8<<<64, 256, 0, stream>>>(z, s0, 16384);

    // SC1: conv 5x5 (2->16), 4 passes of 2 batches
    for (int b0 = 0; b0 < 8; b0 += 2) {
        k_conv1<<<9600, 256, 0, stream>>>(s0, W1, z, b0);
        k_scan_u8<<<128, 256, 0, stream>>>(z, s1 + (size_t)b0 * 16 * 1024 * T_STEPS, 32768);
    }

    // SP1: pool2 (32x32 -> 16x16, 16 ch) + scan
    k_pool2<<<9600, 256, 0, stream>>>(s1, z, 16);
    k_scan_u8<<<128, 256, 0, stream>>>(z, s2, 32768);

    // SC2: conv 3x3 (16->32), 2 passes of 4 batches
    for (int b0 = 0; b0 < 8; b0 += 4) {
        k_conv2<<<9000, 256, 0, stream>>>(s2, W2, z, b0);
        k_scan_u8<<<128, 256, 0, stream>>>(z, s3 + (size_t)b0 * 32 * 256 * T_STEPS, 32768);
    }

    // SP2: pool2 (16x16 -> 8x8, 32 ch) + scan (float spikes for FC)
    k_pool2<<<4800, 256, 0, stream>>>(s3, z, 8);
    k_scan_f32<<<64, 256, 0, stream>>>(z, s4, 16384);

    // SF1: FC 2048->512 + scan (float spikes)
    k_fc1<<<1200, 256, 0, stream>>>(s4, Wf1, z);
    k_scan_f32<<<16, 256, 0, stream>>>(z, s5, 4096);

    // SF2: FC 512->11 + final scan straight into d_out
    k_fc2<<<26, 256, 0, stream>>>(s5, Wf2, z);
    k_scan_f32<<<1, 128, 0, stream>>>(z, out, 88);
}

// Round 2
// 1421.097 us; speedup vs baseline: 1.2553x; 1.2553x over previous
//
#include <hip/hip_runtime.h>
#include <stdint.h>

#define T_STEPS 300
#define T4 75

// ---- scan (psp + spike) constants ----
// d = exp(-1), c = e, cr = -2*theta*e, theta = 10
__device__ __forceinline__ void scan_step(float x, float& pp, float& pq,
                                          float& rp, float& rq, float& s_out) {
    const float D  = 0.36787944117144233f;
    const float C  = 2.7182818284590452f;
    const float CR = -54.365636569180904f;
    const float TH = 10.0f;
    pq = D * (pq + pp);      // psp state (q uses old p -> eps[0]=0)
    pp = D * pp + x;
    float u = C * pq;
    rq = D * (rq + rp);      // refractory state (q uses old p)
    float s = (u + CR * rq >= TH) ? 1.0f : 0.0f;
    rp = D * rp + s;
    s_out = s;
}

__global__ __launch_bounds__(256) void k_scan_u8(const float* __restrict__ z,
                                                 uint8_t* __restrict__ s, int N) {
    int n = blockIdx.x * 256 + threadIdx.x;
    if (n >= N) return;
    const float4* zp = reinterpret_cast<const float4*>(z + (size_t)n * T_STEPS);
    uint8_t* sp = s + (size_t)n * T_STEPS;
    float pp = 0.f, pq = 0.f, rp = 0.f, rq = 0.f;
    for (int it = 0; it < T4; ++it) {
        float4 v = zp[it];
        float s0, s1, s2, s3;
        scan_step(v.x, pp, pq, rp, rq, s0);
        scan_step(v.y, pp, pq, rp, rq, s1);
        scan_step(v.z, pp, pq, rp, rq, s2);
        scan_step(v.w, pp, pq, rp, rq, s3);
        uint32_t pack = (uint32_t)s0 | ((uint32_t)s1 << 8) |
                        ((uint32_t)s2 << 16) | ((uint32_t)s3 << 24);
        *reinterpret_cast<uint32_t*>(sp + it * 4) = pack;
    }
}

// out stride (in floats) parameterized so fc1 can consume a padded layout
__global__ __launch_bounds__(256) void k_scan_f32(const float* __restrict__ z,
                                                  float* __restrict__ s, int N, int ostride) {
    int n = blockIdx.x * blockDim.x + threadIdx.x;
    if (n >= N) return;
    const float4* zp = reinterpret_cast<const float4*>(z + (size_t)n * T_STEPS);
    float* sp = s + (size_t)n * ostride;
    float pp = 0.f, pq = 0.f, rp = 0.f, rq = 0.f;
    for (int it = 0; it < T4; ++it) {
        float4 v = zp[it];
        float4 o;
        scan_step(v.x, pp, pq, rp, rq, o.x);
        scan_step(v.y, pp, pq, rp, rq, o.y);
        scan_step(v.z, pp, pq, rp, rq, o.z);
        scan_step(v.w, pp, pq, rp, rq, o.w);
        *reinterpret_cast<float4*>(sp + it * 4) = o;
    }
}

// ---- SP0 spatial: 4x4 sum-pool * 11 on raw input, t-vectorized ----
__global__ __launch_bounds__(256) void k_pool4(const float* __restrict__ in,
                                               float* __restrict__ z) {
    int idx = blockIdx.x * 256 + threadIdx.x;   // 16384 * 75
    int t4 = idx % T4;
    int n  = idx / T4;                // (b*2+c)*1024 + y*32 + x
    int x = n & 31, y = (n >> 5) & 31, bc = n >> 10;
    const float* base = in + ((size_t)bc * 16384 + (size_t)(4 * y) * 128 + 4 * x) * T_STEPS + 4 * t4;
    float4 acc = {0.f, 0.f, 0.f, 0.f};
#pragma unroll
    for (int i = 0; i < 4; ++i)
#pragma unroll
        for (int j = 0; j < 4; ++j) {
            float4 v = *reinterpret_cast<const float4*>(base + ((size_t)i * 128 + j) * T_STEPS);
            acc.x += v.x; acc.y += v.y; acc.z += v.z; acc.w += v.w;
        }
    float4 o = {11.f * acc.x, 11.f * acc.y, 11.f * acc.z, 11.f * acc.w};
    *reinterpret_cast<float4*>(z + (size_t)n * T_STEPS + 4 * t4) = o;
}

// ---- generic 2x2 sum-pool * 11 on u8 spikes ----
__global__ __launch_bounds__(256) void k_pool2(const uint8_t* __restrict__ s,
                                               float* __restrict__ z, int HW) {
    int idx = blockIdx.x * 256 + threadIdx.x;
    int t4 = idx % T4;
    int n  = idx / T4;
    int x = n % HW;
    int y = (n / HW) % HW;
    int bc = n / (HW * HW);
    int W2d = HW * 2;
    const uint8_t* base = s + ((size_t)bc * W2d * W2d + (size_t)(2 * y) * W2d + 2 * x) * T_STEPS + 4 * t4;
    uint32_t v00 = *reinterpret_cast<const uint32_t*>(base);
    uint32_t v01 = *reinterpret_cast<const uint32_t*>(base + T_STEPS);
    uint32_t v10 = *reinterpret_cast<const uint32_t*>(base + (size_t)W2d * T_STEPS);
    uint32_t v11 = *reinterpret_cast<const uint32_t*>(base + (size_t)(W2d + 1) * T_STEPS);
    float4 o;
    o.x = 11.f * (float)((v00 & 0xffu) + (v01 & 0xffu) + (v10 & 0xffu) + (v11 & 0xffu));
    o.y = 11.f * (float)(((v00 >> 8) & 0xffu) + ((v01 >> 8) & 0xffu) + ((v10 >> 8) & 0xffu) + ((v11 >> 8) & 0xffu));
    o.z = 11.f * (float)(((v00 >> 16) & 0xffu) + ((v01 >> 16) & 0xffu) + ((v10 >> 16) & 0xffu) + ((v11 >> 16) & 0xffu));
    o.w = 11.f * (float)((v00 >> 24) + (v01 >> 24) + (v10 >> 24) + (v11 >> 24));
    *reinterpret_cast<float4*>(z + (size_t)n * T_STEPS + 4 * t4) = o;
}

// ---- SC1: 5x5 conv, 2->16, 32x32, pad 2, over 2 b's per pass ----
__global__ __launch_bounds__(256) void k_conv1(const uint8_t* __restrict__ s0,
                                               const float* __restrict__ W1,
                                               float* __restrict__ z, int b0) {
    int idx = blockIdx.x * 256 + threadIdx.x;   // 2*16*1024*75
    int t4 = idx % T4;
    int r  = idx / T4;            // ((bb*16+o)*32+y)*32+x
    int x = r & 31, y = (r >> 5) & 31, o = (r >> 10) & 15, bb = r >> 14;
    int b = b0 + bb;
    float a0 = 0.f, a1 = 0.f, a2 = 0.f, a3 = 0.f;
#pragma unroll
    for (int c = 0; c < 2; ++c) {
        float w[25];
#pragma unroll
        for (int j = 0; j < 25; ++j) w[j] = W1[(o * 2 + c) * 25 + j];
        const uint8_t* cbase = s0 + ((size_t)(b * 2 + c) * 1024) * T_STEPS + 4 * t4;
#pragma unroll
        for (int ky = 0; ky < 5; ++ky) {
            int yy = y + ky - 2;
            if (yy < 0 || yy >= 32) continue;
#pragma unroll
            for (int kx = 0; kx < 5; ++kx) {
                int xx = x + kx - 2;
                if (xx < 0 || xx >= 32) continue;
                uint32_t v = *reinterpret_cast<const uint32_t*>(cbase + (size_t)(yy * 32 + xx) * T_STEPS);
                float wv = w[ky * 5 + kx];
                a0 = fmaf(wv, (float)(v & 0xffu), a0);
                a1 = fmaf(wv, (float)((v >> 8) & 0xffu), a1);
                a2 = fmaf(wv, (float)((v >> 16) & 0xffu), a2);
                a3 = fmaf(wv, (float)(v >> 24), a3);
            }
        }
    }
    *reinterpret_cast<float4*>(z + (size_t)r * T_STEPS + 4 * t4) = make_float4(a0, a1, a2, a3);
}

// ---- SC2: 3x3 conv, 16->32, 16x16, pad 1, over 4 b's per pass ----
__global__ __launch_bounds__(256) void k_conv2(const uint8_t* __restrict__ s2,
                                               const float* __restrict__ W2,
                                               float* __restrict__ z, int b0) {
    int idx = blockIdx.x * 256 + threadIdx.x;   // 4*32*256*75
    int t4 = idx % T4;
    int r  = idx / T4;            // ((bb*32+o)*16+y)*16+x
    int x = r & 15, y = (r >> 4) & 15, o = (r >> 8) & 31, bb = r >> 13;
    int b = b0 + bb;
    float a0 = 0.f, a1 = 0.f, a2 = 0.f, a3 = 0.f;
#pragma unroll
    for (int cc = 0; cc < 4; ++cc) {          // 4 channels per chunk
        float w[36];
#pragma unroll
        for (int j = 0; j < 36; ++j) w[j] = W2[o * 144 + cc * 36 + j];
#pragma unroll
        for (int ci = 0; ci < 4; ++ci) {
            int c = cc * 4 + ci;
            const uint8_t* cbase = s2 + ((size_t)(b * 16 + c) * 256) * T_STEPS + 4 * t4;
#pragma unroll
            for (int ky = 0; ky < 3; ++ky) {
                int yy = y + ky - 1;
                if (yy < 0 || yy >= 16) continue;
#pragma unroll
                for (int kx = 0; kx < 3; ++kx) {
                    int xx = x + kx - 1;
                    if (xx < 0 || xx >= 16) continue;
                    uint32_t v = *reinterpret_cast<const uint32_t*>(cbase + (size_t)(yy * 16 + xx) * T_STEPS);
                    float wv = w[ci * 9 + ky * 3 + kx];
                    a0 = fmaf(wv, (float)(v & 0xffu), a0);
                    a1 = fmaf(wv, (float)((v >> 8) & 0xffu), a1);
                    a2 = fmaf(wv, (float)((v >> 16) & 0xffu), a2);
                    a3 = fmaf(wv, (float)(v >> 24), a3);
                }
            }
        }
    }
    *reinterpret_cast<float4*>(z + (size_t)r * T_STEPS + 4 * t4) = make_float4(a0, a1, a2, a3);
}

// ---- SF1 as LDS-tiled fp32 GEMM ----
// C[o, t] = sum_k Wf1[o,k] * s4[b,k,t];  M=512, K=2048, N=300 per batch.
// Block tile: 128 o x 32 t (8 t4), K-step 32.  s4 padded to 80 t4 per row.
// grid = (10 t-tiles, 4 o-tiles, 8 b), 256 threads.
#define FC1_S4_T4 80          // padded t4 stride of s4
__global__ __launch_bounds__(256) void k_fc1_gemm(const float* __restrict__ s4,
                                                  const float* __restrict__ Wf1,
                                                  float* __restrict__ z) {
    __shared__ float Wt[32][128];      // [kk][o] 16 KB
    __shared__ float At[32][32];       // [kk][t]  4 KB

    int tt = blockIdx.x;               // 0..9
    int ot = blockIdx.y;               // 0..3
    int b  = blockIdx.z;               // 0..7
    int tid = threadIdx.x;
    int othr = tid >> 3;               // 0..31
    int tthr = tid & 7;                // 0..7
    int o0 = othr * 4;
    int t4g = tt * 8 + tthr;           // global (padded) t4 index, 0..79

    // staging index precompute
    int wo = tid >> 1, wh = tid & 1;   // W: row wo, k-half wh
    const float* wrow = Wf1 + (size_t)(ot * 128 + wo) * 2048 + wh * 16;
    int akk = tid >> 3;                // A: k row within tile
    const float* abase = s4 + (size_t)(b * 2048 + akk) * (FC1_S4_T4 * 4) + (size_t)(tt * 8 + tthr) * 4;

    float4 acc0 = {0,0,0,0}, acc1 = {0,0,0,0}, acc2 = {0,0,0,0}, acc3 = {0,0,0,0};

    // prologue: load k-step 0 into registers
    float4 wr0 = *reinterpret_cast<const float4*>(wrow + 0);
    float4 wr1 = *reinterpret_cast<const float4*>(wrow + 4);
    float4 wr2 = *reinterpret_cast<const float4*>(wrow + 8);
    float4 wr3 = *reinterpret_cast<const float4*>(wrow + 12);
    float4 ar  = *reinterpret_cast<const float4*>(abase);

    for (int ks = 0; ks < 64; ++ks) {
        __syncthreads();               // previous compute done before overwrite
        int kb = wh * 16;
        Wt[kb + 0][wo] = wr0.x;  Wt[kb + 1][wo] = wr0.y;  Wt[kb + 2][wo] = wr0.z;  Wt[kb + 3][wo] = wr0.w;
        Wt[kb + 4][wo] = wr1.x;  Wt[kb + 5][wo] = wr1.y;  Wt[kb + 6][wo] = wr1.z;  Wt[kb + 7][wo] = wr1.w;
        Wt[kb + 8][wo] = wr2.x;  Wt[kb + 9][wo] = wr2.y;  Wt[kb +10][wo] = wr2.z;  Wt[kb +11][wo] = wr2.w;
        Wt[kb +12][wo] = wr3.x;  Wt[kb +13][wo] = wr3.y;  Wt[kb +14][wo] = wr3.z;  Wt[kb +15][wo] = wr3.w;
        *reinterpret_cast<float4*>(&At[akk][tthr * 4]) = ar;
        __syncthreads();
        if (ks < 63) {                 // prefetch next k-step while computing
            int k0 = (ks + 1) * 32;
            wr0 = *reinterpret_cast<const float4*>(wrow + k0 + 0);
            wr1 = *reinterpret_cast<const float4*>(wrow + k0 + 4);
            wr2 = *reinterpret_cast<const float4*>(wrow + k0 + 8);
            wr3 = *reinterpret_cast<const float4*>(wrow + k0 + 12);
            ar  = *reinterpret_cast<const float4*>(abase + (size_t)k0 * (FC1_S4_T4 * 4));
        }
#pragma unroll
        for (int kk = 0; kk < 32; ++kk) {
            float4 wv = *reinterpret_cast<const float4*>(&Wt[kk][o0]);
            float4 av = *reinterpret_cast<const float4*>(&At[kk][tthr * 4]);
            acc0.x = fmaf(wv.x, av.x, acc0.x); acc0.y = fmaf(wv.x, av.y, acc0.y);
            acc0.z = fmaf(wv.x, av.z, acc0.z); acc0.w = fmaf(wv.x, av.w, acc0.w);
            acc1.x = fmaf(wv.y, av.x, acc1.x); acc1.y = fmaf(wv.y, av.y, acc1.y);
            acc1.z = fmaf(wv.y, av.z, acc1.z); acc1.w = fmaf(wv.y, av.w, acc1.w);
            acc2.x = fmaf(wv.z, av.x, acc2.x); acc2.y = fmaf(wv.z, av.y, acc2.y);
            acc2.z = fmaf(wv.z, av.z, acc2.z); acc2.w = fmaf(wv.z, av.w, acc2.w);
            acc3.x = fmaf(wv.w, av.x, acc3.x); acc3.y = fmaf(wv.w, av.y, acc3.y);
            acc3.z = fmaf(wv.w, av.z, acc3.z); acc3.w = fmaf(wv.w, av.w, acc3.w);
        }
    }

    if (t4g < T4) {
        size_t orow = (size_t)(b * 512 + ot * 128 + o0);
        *reinterpret_cast<float4*>(z + (orow + 0) * T_STEPS + t4g * 4) = acc0;
        *reinterpret_cast<float4*>(z + (orow + 1) * T_STEPS + t4g * 4) = acc1;
        *reinterpret_cast<float4*>(z + (orow + 2) * T_STEPS + t4g * 4) = acc2;
        *reinterpret_cast<float4*>(z + (orow + 3) * T_STEPS + t4g * 4) = acc3;
    }
}

// ---- SF2: 512 -> 11 FC ----
__global__ __launch_bounds__(256) void k_fc2(const float* __restrict__ s5,
                                             const float* __restrict__ Wf2,
                                             float* __restrict__ z) {
    int idx = blockIdx.x * 256 + threadIdx.x;   // 11*8*75 = 6600
    if (idx >= 6600) return;
    int t4 = idx % T4;
    int r  = idx / T4;            // o*8 + b
    int b = r & 7, o = r >> 3;
    const float* sp = s5 + (size_t)b * 512 * T_STEPS + 4 * t4;
    const float* wp = Wf2 + (size_t)o * 512;
    float a0 = 0.f, a1 = 0.f, a2 = 0.f, a3 = 0.f;
#pragma unroll 2
    for (int k = 0; k < 512; k += 4) {
        float4 wv = *reinterpret_cast<const float4*>(wp + k);
        float4 v0 = *reinterpret_cast<const float4*>(sp + (size_t)(k + 0) * T_STEPS);
        float4 v1 = *reinterpret_cast<const float4*>(sp + (size_t)(k + 1) * T_STEPS);
        float4 v2 = *reinterpret_cast<const float4*>(sp + (size_t)(k + 2) * T_STEPS);
        float4 v3 = *reinterpret_cast<const float4*>(sp + (size_t)(k + 3) * T_STEPS);
        a0 = fmaf(wv.x, v0.x, a0); a1 = fmaf(wv.x, v0.y, a1); a2 = fmaf(wv.x, v0.z, a2); a3 = fmaf(wv.x, v0.w, a3);
        a0 = fmaf(wv.y, v1.x, a0); a1 = fmaf(wv.y, v1.y, a1); a2 = fmaf(wv.y, v1.z, a2); a3 = fmaf(wv.y, v1.w, a3);
        a0 = fmaf(wv.z, v2.x, a0); a1 = fmaf(wv.z, v2.y, a1); a2 = fmaf(wv.z, v2.z, a2); a3 = fmaf(wv.z, v2.w, a3);
        a0 = fmaf(wv.w, v3.x, a0); a1 = fmaf(wv.w, v3.y, a1); a2 = fmaf(wv.w, v3.z, a2); a3 = fmaf(wv.w, v3.w, a3);
    }
    *reinterpret_cast<float4*>(z + (size_t)(b * 11 + o) * T_STEPS + 4 * t4) = make_float4(a0, a1, a2, a3);
}

__global__ void k_zero(float* out, int n) {
    int i = blockIdx.x * 256 + threadIdx.x;
    if (i < n) out[i] = 0.f;
}

extern "C" void kernel_launch(void* const* d_in, const int* in_sizes, int n_in,
                              void* d_out, int out_size, void* d_ws, size_t ws_size,
                              hipStream_t stream) {
    const float* s_in = (const float*)d_in[0];
    const float* W1   = (const float*)d_in[1];
    const float* W2   = (const float*)d_in[2];
    const float* Wf1  = (const float*)d_in[3];
    const float* Wf2  = (const float*)d_in[4];
    float* out = (float*)d_out;

    // workspace layout (bytes)
    const size_t OFF_Z  = 0;               // 39,321,600 B (reused per stage)
    const size_t OFF_S0 = 39321600;        // u8,  4,915,200
    const size_t OFF_S1 = 44236800;        // u8, 39,321,600
    const size_t OFF_S2 = 83558400;        // u8,  9,830,400
    const size_t OFF_S3 = 93388800;        // u8, 19,660,800
    const size_t OFF_S4 = 113049600;       // f32 padded [8][2048][320] = 20,971,520
    const size_t OFF_S5 = 8000000;         // f32 4,915,200 — lives inside z region
                                           // (fc1's z use = 4.9 MB at offset 0; no overlap)
    const size_t NEEDED = 134021120;

    if (ws_size < NEEDED) {   // graceful failure path (deterministic)
        k_zero<<<(26400 + 255) / 256, 256, 0, stream>>>(out, 26400);
        return;
    }

    char* ws = (char*)d_ws;
    float*   z  = (float*)(ws + OFF_Z);
    uint8_t* s0 = (uint8_t*)(ws + OFF_S0);
    uint8_t* s1 = (uint8_t*)(ws + OFF_S1);
    uint8_t* s2 = (uint8_t*)(ws + OFF_S2);
    uint8_t* s3 = (uint8_t*)(ws + OFF_S3);
    float*   s4 = (float*)(ws + OFF_S4);
    float*   s5 = (float*)(ws + OFF_S5);

    // SP0: pool4 + scan
    k_pool4<<<4800, 256, 0, stream>>>(s_in, z);
    k_scan_u8<<<64, 256, 0, stream>>>(z, s0, 16384);

    // SC1: conv 5x5 (2->16), 4 passes of 2 batches
    for (int b0 = 0; b0 < 8; b0 += 2) {
        k_conv1<<<9600, 256, 0, stream>>>(s0, W1, z, b0);
        k_scan_u8<<<128, 256, 0, stream>>>(z, s1 + (size_t)b0 * 16 * 1024 * T_STEPS, 32768);
    }

    // SP1: pool2 (32x32 -> 16x16, 16 ch) + scan
    k_pool2<<<9600, 256, 0, stream>>>(s1, z, 16);
    k_scan_u8<<<128, 256, 0, stream>>>(z, s2, 32768);

    // SC2: conv 3x3 (16->32), 2 passes of 4 batches
    for (int b0 = 0; b0 < 8; b0 += 4) {
        k_conv2<<<9000, 256, 0, stream>>>(s2, W2, z, b0);
        k_scan_u8<<<128, 256, 0, stream>>>(z, s3 + (size_t)b0 * 32 * 256 * T_STEPS, 32768);
    }

    // SP2: pool2 (16x16 -> 8x8, 32 ch) + scan (float spikes, padded stride 320)
    k_pool2<<<4800, 256, 0, stream>>>(s3, z, 8);
    k_scan_f32<<<64, 256, 0, stream>>>(z, s4, 16384, 320);

    // SF1: tiled GEMM 2048->512 + scan (float spikes into z-region alias)
    k_fc1_gemm<<<dim3(10, 4, 8), 256, 0, stream>>>(s4, Wf1, z);
    k_scan_f32<<<16, 256, 0, stream>>>(z, s5, 4096, 300);

    // SF2: FC 512->11 + final scan straight into d_out
    k_fc2<<<26, 256, 0, stream>>>(s5, Wf2, z);
    k_scan_f32<<<1, 128, 0, stream>>>(z, out, 88, 300);
}

// Round 3
// 965.795 us; speedup vs baseline: 1.8471x; 1.4714x over previous
//
#include <hip/hip_runtime.h>
#include <stdint.h>

#define T_STEPS 300
#define T4 75

// ---- scan (psp + spike) constants: d = exp(-1), c = e, cr = -2*theta*e ----
__device__ __forceinline__ void scan_step(float x, float& pp, float& pq,
                                          float& rp, float& rq, float& s_out) {
    const float D  = 0.36787944117144233f;
    const float C  = 2.7182818284590452f;
    const float CR = -54.365636569180904f;
    const float TH = 10.0f;
    pq = D * (pq + pp);      // psp state (q uses old p)
    pp = D * pp + x;
    float u = C * pq;
    rq = D * (rq + rp);      // refractory state
    float s = (u + CR * rq >= TH) ? 1.0f : 0.0f;
    rp = D * rp + s;
    s_out = s;
}

#define SCAN4(v, PACK)                                                     \
    {                                                                      \
        float s0, s1, s2, s3;                                              \
        scan_step(v.x, pp, pq, rp, rq, s0);                                \
        scan_step(v.y, pp, pq, rp, rq, s1);                                \
        scan_step(v.z, pp, pq, rp, rq, s2);                                \
        scan_step(v.w, pp, pq, rp, rq, s3);                                \
        PACK = (uint32_t)s0 | ((uint32_t)s1 << 8) |                        \
               ((uint32_t)s2 << 16) | ((uint32_t)s3 << 24);                \
    }

#define FMA4(A, wc) A.x = fmaf(wc, f0, A.x); A.y = fmaf(wc, f1, A.y); \
                    A.z = fmaf(wc, f2, A.z); A.w = fmaf(wc, f3, A.w);

// ---- SP0 spatial: 4x4 sum-pool * 11 on raw input (t-major z out) ----
__global__ __launch_bounds__(256) void k_pool4(const float* __restrict__ in,
                                               float* __restrict__ z) {
    int idx = blockIdx.x * 256 + threadIdx.x;   // 16384 * 75
    int t4 = idx % T4;
    int n  = idx / T4;                // (b*2+c)*1024 + y*32 + x
    int x = n & 31, y = (n >> 5) & 31, bc = n >> 10;
    const float* base = in + ((size_t)bc * 16384 + (size_t)(4 * y) * 128 + 4 * x) * T_STEPS + 4 * t4;
    float4 acc = {0.f, 0.f, 0.f, 0.f};
#pragma unroll
    for (int i = 0; i < 4; ++i)
#pragma unroll
        for (int j = 0; j < 4; ++j) {
            float4 v = *reinterpret_cast<const float4*>(base + ((size_t)i * 128 + j) * T_STEPS);
            acc.x += v.x; acc.y += v.y; acc.z += v.z; acc.w += v.w;
        }
    float4 o = {11.f * acc.x, 11.f * acc.y, 11.f * acc.z, 11.f * acc.w};
    *reinterpret_cast<float4*>(z + (size_t)n * T_STEPS + 4 * t4) = o;
}

// ---- scan: t-major f32 z in -> u32 spike planes out ----
__global__ __launch_bounds__(256) void k_scan_l0(const float* __restrict__ z,
                                                 uint32_t* __restrict__ sp, int N) {
    int n = blockIdx.x * 256 + threadIdx.x;
    if (n >= N) return;
    const float4* zp = reinterpret_cast<const float4*>(z + (size_t)n * T_STEPS);
    float pp = 0.f, pq = 0.f, rp = 0.f, rq = 0.f;
#pragma unroll 2
    for (int t4 = 0; t4 < T4; ++t4) {
        float4 v = zp[t4];
        uint32_t pack;
        SCAN4(v, pack);
        sp[(size_t)t4 * N + n] = pack;
    }
}

// ---- scan: f4 z planes in -> u32 spike planes out ----
__global__ __launch_bounds__(256) void k_scan_plane(const float4* __restrict__ z,
                                                    uint32_t* __restrict__ sp, int N) {
    int n = blockIdx.x * 256 + threadIdx.x;
    if (n >= N) return;
    float pp = 0.f, pq = 0.f, rp = 0.f, rq = 0.f;
#pragma unroll 2
    for (int t4 = 0; t4 < T4; ++t4) {
        float4 v = z[(size_t)t4 * N + n];
        uint32_t pack;
        SCAN4(v, pack);
        sp[(size_t)t4 * N + n] = pack;
    }
}

// ---- scan: t-major f32 z in -> t-major f32 spikes out (FC tail) ----
__global__ __launch_bounds__(256) void k_scan_f32(const float* __restrict__ z,
                                                  float* __restrict__ s, int N, int ostride) {
    int n = blockIdx.x * blockDim.x + threadIdx.x;
    if (n >= N) return;
    const float4* zp = reinterpret_cast<const float4*>(z + (size_t)n * T_STEPS);
    float* spo = s + (size_t)n * ostride;
    float pp = 0.f, pq = 0.f, rp = 0.f, rq = 0.f;
    for (int it = 0; it < T4; ++it) {
        float4 v = zp[it];
        float4 o;
        scan_step(v.x, pp, pq, rp, rq, o.x);
        scan_step(v.y, pp, pq, rp, rq, o.y);
        scan_step(v.z, pp, pq, rp, rq, o.z);
        scan_step(v.w, pp, pq, rp, rq, o.w);
        *reinterpret_cast<float4*>(spo + it * 4) = o;
    }
}

// ---- fused 2x2 sum-pool * 11 + scan on u32 spike planes ----
template<int HW, int NIN, int NOUT>
__global__ __launch_bounds__(256) void k_pool2s(const uint32_t* __restrict__ sin,
                                                uint32_t* __restrict__ sout) {
    int n = blockIdx.x * 256 + threadIdx.x;
    if (n >= NOUT) return;
    int x = n % HW, y = (n / HW) % HW, bc = n / (HW * HW);
    const int W2d = HW * 2;
    const uint32_t* base0 = sin + (size_t)bc * W2d * W2d + (size_t)(2 * y) * W2d + 2 * x;
    float pp = 0.f, pq = 0.f, rp = 0.f, rq = 0.f;
#pragma unroll 2
    for (int t4 = 0; t4 < T4; ++t4) {
        const uint32_t* p = base0 + (size_t)t4 * NIN;
        uint32_t sum = p[0] + p[1] + p[W2d] + p[W2d + 1];  // SWAR, bytes <= 4
        float4 v;
        v.x = 11.f * (float)(sum & 0xffu);
        v.y = 11.f * (float)((sum >> 8) & 0xffu);
        v.z = 11.f * (float)((sum >> 16) & 0xffu);
        v.w = 11.f * (float)(sum >> 24);
        uint32_t pack;
        SCAN4(v, pack);
        sout[(size_t)t4 * NOUT + n] = pack;
    }
}

// ---- SC1: 5x5 conv 2->16 over 32x32; thread = (b,pix,t4), ALL 16 o in regs ----
__global__ __launch_bounds__(256) void k_conv1(const uint32_t* __restrict__ s0p,
                                               const float* __restrict__ W1,
                                               float4* __restrict__ z1p) {
    __shared__ float w_lds[2][25][16];
    int bid = blockIdx.x;               // 2400
    int pixblk = bid & 3;
    int t4 = (bid >> 2) % 75;
    int b  = bid / 300;
    int tid = threadIdx.x;
    for (int j = tid; j < 800; j += 256) {
        int o = j & 15, kk = (j >> 4) % 25, c = j / 400;
        w_lds[c][kk][o] = W1[(o * 2 + c) * 25 + kk];
    }
    __syncthreads();
    int pix = pixblk * 256 + tid;
    int px = pix & 31, py = pix >> 5;
    float4 acc[16];
#pragma unroll
    for (int o = 0; o < 16; ++o) acc[o] = make_float4(0.f, 0.f, 0.f, 0.f);
    const uint32_t* pb = s0p + (size_t)t4 * 16384 + (size_t)(b * 2) * 1024;
    for (int c = 0; c < 2; ++c) {
#pragma unroll
        for (int ky = 0; ky < 5; ++ky) {
            int yy = py + ky - 2;
            bool rok = (unsigned)yy < 32u;
#pragma unroll
            for (int kx = 0; kx < 5; ++kx) {
                int xx = px + kx - 2;
                uint32_t v = 0;
                if (rok && (unsigned)xx < 32u) v = pb[c * 1024 + yy * 32 + xx];
                float f0 = (float)(v & 0xffu), f1 = (float)((v >> 8) & 0xffu);
                float f2 = (float)((v >> 16) & 0xffu), f3 = (float)(v >> 24);
                int kk = ky * 5 + kx;
#pragma unroll
                for (int oo = 0; oo < 4; ++oo) {
                    float4 w4 = *reinterpret_cast<const float4*>(&w_lds[c][kk][oo * 4]);
                    FMA4(acc[oo * 4 + 0], w4.x);
                    FMA4(acc[oo * 4 + 1], w4.y);
                    FMA4(acc[oo * 4 + 2], w4.z);
                    FMA4(acc[oo * 4 + 3], w4.w);
                }
            }
        }
    }
    size_t zb = (size_t)t4 * 131072 + (size_t)(b * 16) * 1024 + pix;
#pragma unroll
    for (int o = 0; o < 16; ++o) z1p[zb + o * 1024] = acc[o];
}

// ---- SC2: 3x3 conv 16->32 over 16x16; thread = (b,pix,t4), 16 o per half ----
__global__ __launch_bounds__(256) void k_conv2(const uint32_t* __restrict__ s2p,
                                               const float* __restrict__ W2,
                                               float4* __restrict__ z2p) {
    __shared__ float w_lds[16][9][16];
    int bid = blockIdx.x;               // 1200
    int oh = bid & 1;
    int t4 = (bid >> 1) % 75;
    int b  = bid / 150;
    int tid = threadIdx.x;              // pix (16x16)
    for (int j = tid; j < 2304; j += 256) {
        int o = j & 15;
        int t9 = (j >> 4) % 9;
        int c  = j / 144;
        w_lds[c][t9][o] = W2[(size_t)((oh * 16 + o) * 16 + c) * 9 + t9];
    }
    __syncthreads();
    int px = tid & 15, py = tid >> 4;
    float4 acc[16];
#pragma unroll
    for (int o = 0; o < 16; ++o) acc[o] = make_float4(0.f, 0.f, 0.f, 0.f);
    const uint32_t* pb = s2p + (size_t)t4 * 32768 + (size_t)(b * 16) * 256;
    for (int c = 0; c < 16; ++c) {
#pragma unroll
        for (int ky = 0; ky < 3; ++ky) {
            int yy = py + ky - 1;
            bool rok = (unsigned)yy < 16u;
#pragma unroll
            for (int kx = 0; kx < 3; ++kx) {
                int xx = px + kx - 1;
                uint32_t v = 0;
                if (rok && (unsigned)xx < 16u) v = pb[c * 256 + yy * 16 + xx];
                float f0 = (float)(v & 0xffu), f1 = (float)((v >> 8) & 0xffu);
                float f2 = (float)((v >> 16) & 0xffu), f3 = (float)(v >> 24);
                int t9 = ky * 3 + kx;
#pragma unroll
                for (int oo = 0; oo < 4; ++oo) {
                    float4 w4 = *reinterpret_cast<const float4*>(&w_lds[c][t9][oo * 4]);
                    FMA4(acc[oo * 4 + 0], w4.x);
                    FMA4(acc[oo * 4 + 1], w4.y);
                    FMA4(acc[oo * 4 + 2], w4.z);
                    FMA4(acc[oo * 4 + 3], w4.w);
                }
            }
        }
    }
    size_t zb = (size_t)t4 * 65536 + (size_t)(b * 32 + oh * 16) * 256 + tid;
#pragma unroll
    for (int o = 0; o < 16; ++o) z2p[zb + o * 256] = acc[o];
}

// ---- SF1 LDS-tiled GEMM; A staged from u32 spike planes ----
__global__ __launch_bounds__(256) void k_fc1_gemm(const uint32_t* __restrict__ s4p,
                                                  const float* __restrict__ Wf1,
                                                  float* __restrict__ z) {
    __shared__ float Wt[32][128];      // [kk][o]
    __shared__ float At[32][32];       // [kk][t]

    int tt = blockIdx.x;               // 0..9
    int ot = blockIdx.y;               // 0..3
    int b  = blockIdx.z;               // 0..7
    int tid = threadIdx.x;
    int othr = tid >> 3, tthr = tid & 7;
    int o0 = othr * 4;
    int t4g = tt * 8 + tthr;

    int wo = tid >> 1, wh = tid & 1;
    const float* wrow = Wf1 + (size_t)(ot * 128 + wo) * 2048 + wh * 16;
    int akk = tid & 31, at4 = tid >> 5;
    int at4g = tt * 8 + at4;
    bool aok = at4g < T4;
    const uint32_t* abase = s4p + (size_t)(aok ? at4g : 0) * 16384 + b * 2048 + akk;

    float4 acc0 = {0,0,0,0}, acc1 = {0,0,0,0}, acc2 = {0,0,0,0}, acc3 = {0,0,0,0};

    float4 wr0 = *reinterpret_cast<const float4*>(wrow + 0);
    float4 wr1 = *reinterpret_cast<const float4*>(wrow + 4);
    float4 wr2 = *reinterpret_cast<const float4*>(wrow + 8);
    float4 wr3 = *reinterpret_cast<const float4*>(wrow + 12);
    uint32_t av = aok ? abase[0] : 0u;

    for (int ks = 0; ks < 64; ++ks) {
        __syncthreads();
        int kb = wh * 16;
        Wt[kb + 0][wo] = wr0.x;  Wt[kb + 1][wo] = wr0.y;  Wt[kb + 2][wo] = wr0.z;  Wt[kb + 3][wo] = wr0.w;
        Wt[kb + 4][wo] = wr1.x;  Wt[kb + 5][wo] = wr1.y;  Wt[kb + 6][wo] = wr1.z;  Wt[kb + 7][wo] = wr1.w;
        Wt[kb + 8][wo] = wr2.x;  Wt[kb + 9][wo] = wr2.y;  Wt[kb +10][wo] = wr2.z;  Wt[kb +11][wo] = wr2.w;
        Wt[kb +12][wo] = wr3.x;  Wt[kb +13][wo] = wr3.y;  Wt[kb +14][wo] = wr3.z;  Wt[kb +15][wo] = wr3.w;
        float4 af;
        af.x = (float)(av & 0xffu);  af.y = (float)((av >> 8) & 0xffu);
        af.z = (float)((av >> 16) & 0xffu);  af.w = (float)(av >> 24);
        *reinterpret_cast<float4*>(&At[akk][at4 * 4]) = af;
        __syncthreads();
        if (ks < 63) {
            int k0 = (ks + 1) * 32;
            wr0 = *reinterpret_cast<const float4*>(wrow + k0 + 0);
            wr1 = *reinterpret_cast<const float4*>(wrow + k0 + 4);
            wr2 = *reinterpret_cast<const float4*>(wrow + k0 + 8);
            wr3 = *reinterpret_cast<const float4*>(wrow + k0 + 12);
            av = aok ? abase[k0] : 0u;
        }
#pragma unroll
        for (int kk = 0; kk < 32; ++kk) {
            float4 wv = *reinterpret_cast<const float4*>(&Wt[kk][o0]);
            float4 avv = *reinterpret_cast<const float4*>(&At[kk][tthr * 4]);
            acc0.x = fmaf(wv.x, avv.x, acc0.x); acc0.y = fmaf(wv.x, avv.y, acc0.y);
            acc0.z = fmaf(wv.x, avv.z, acc0.z); acc0.w = fmaf(wv.x, avv.w, acc0.w);
            acc1.x = fmaf(wv.y, avv.x, acc1.x); acc1.y = fmaf(wv.y, avv.y, acc1.y);
            acc1.z = fmaf(wv.y, avv.z, acc1.z); acc1.w = fmaf(wv.y, avv.w, acc1.w);
            acc2.x = fmaf(wv.z, avv.x, acc2.x); acc2.y = fmaf(wv.z, avv.y, acc2.y);
            acc2.z = fmaf(wv.z, avv.z, acc2.z); acc2.w = fmaf(wv.z, avv.w, acc2.w);
            acc3.x = fmaf(wv.w, avv.x, acc3.x); acc3.y = fmaf(wv.w, avv.y, acc3.y);
            acc3.z = fmaf(wv.w, avv.z, acc3.z); acc3.w = fmaf(wv.w, avv.w, acc3.w);
        }
    }

    if (t4g < T4) {
        size_t orow = (size_t)(b * 512 + ot * 128 + o0);
        *reinterpret_cast<float4*>(z + (orow + 0) * T_STEPS + t4g * 4) = acc0;
        *reinterpret_cast<float4*>(z + (orow + 1) * T_STEPS + t4g * 4) = acc1;
        *reinterpret_cast<float4*>(z + (orow + 2) * T_STEPS + t4g * 4) = acc2;
        *reinterpret_cast<float4*>(z + (orow + 3) * T_STEPS + t4g * 4) = acc3;
    }
}

// ---- SF2: 512 -> 11 FC (t-major f32 spikes) ----
__global__ __launch_bounds__(256) void k_fc2(const float* __restrict__ s5,
                                             const float* __restrict__ Wf2,
                                             float* __restrict__ z) {
    int idx = blockIdx.x * 256 + threadIdx.x;   // 11*8*75 = 6600
    if (idx >= 6600) return;
    int t4 = idx % T4;
    int r  = idx / T4;            // o*8 + b
    int b = r & 7, o = r >> 3;
    const float* sp = s5 + (size_t)b * 512 * T_STEPS + 4 * t4;
    const float* wp = Wf2 + (size_t)o * 512;
    float a0 = 0.f, a1 = 0.f, a2 = 0.f, a3 = 0.f;
#pragma unroll 2
    for (int k = 0; k < 512; k += 4) {
        float4 wv = *reinterpret_cast<const float4*>(wp + k);
        float4 v0 = *reinterpret_cast<const float4*>(sp + (size_t)(k + 0) * T_STEPS);
        float4 v1 = *reinterpret_cast<const float4*>(sp + (size_t)(k + 1) * T_STEPS);
        float4 v2 = *reinterpret_cast<const float4*>(sp + (size_t)(k + 2) * T_STEPS);
        float4 v3 = *reinterpret_cast<const float4*>(sp + (size_t)(k + 3) * T_STEPS);
        a0 = fmaf(wv.x, v0.x, a0); a1 = fmaf(wv.x, v0.y, a1); a2 = fmaf(wv.x, v0.z, a2); a3 = fmaf(wv.x, v0.w, a3);
        a0 = fmaf(wv.y, v1.x, a0); a1 = fmaf(wv.y, v1.y, a1); a2 = fmaf(wv.y, v1.z, a2); a3 = fmaf(wv.y, v1.w, a3);
        a0 = fmaf(wv.z, v2.x, a0); a1 = fmaf(wv.z, v2.y, a1); a2 = fmaf(wv.z, v2.z, a2); a3 = fmaf(wv.z, v2.w, a3);
        a0 = fmaf(wv.w, v3.x, a0); a1 = fmaf(wv.w, v3.y, a1); a2 = fmaf(wv.w, v3.z, a2); a3 = fmaf(wv.w, v3.w, a3);
    }
    *reinterpret_cast<float4*>(z + (size_t)(b * 11 + o) * T_STEPS + 4 * t4) = make_float4(a0, a1, a2, a3);
}

__global__ void k_zero(float* out, int n) {
    int i = blockIdx.x * 256 + threadIdx.x;
    if (i < n) out[i] = 0.f;
}

extern "C" void kernel_launch(void* const* d_in, const int* in_sizes, int n_in,
                              void* d_out, int out_size, void* d_ws, size_t ws_size,
                              hipStream_t stream) {
    const float* s_in = (const float*)d_in[0];
    const float* W1   = (const float*)d_in[1];
    const float* W2   = (const float*)d_in[2];
    const float* Wf1  = (const float*)d_in[3];
    const float* Wf2  = (const float*)d_in[4];
    float* out = (float*)d_out;

    // workspace layout (bytes); Z region reused by every stage's membrane drive
    const size_t OFF_Z  = 0;               // max 157,286,400 (conv1 z planes)
    const size_t OFF_S0 = 157286400;       // u32 planes,  4,915,200
    const size_t OFF_S1 = 162201600;       // u32 planes, 39,321,600
    const size_t OFF_S2 = 201523200;       // u32 planes,  9,830,400
    const size_t OFF_S3 = 211353600;       // u32 planes, 19,660,800
    const size_t OFF_S4 = 231014400;       // u32 planes,  4,915,200
    const size_t OFF_S5 = 235929600;       // f32 t-major, 4,915,200
    const size_t NEEDED = 240844800;

    if (ws_size < NEEDED) {
        k_zero<<<(26400 + 255) / 256, 256, 0, stream>>>(out, 26400);
        return;
    }

    char* ws = (char*)d_ws;
    float*    Z   = (float*)(ws + OFF_Z);
    uint32_t* s0p = (uint32_t*)(ws + OFF_S0);
    uint32_t* s1p = (uint32_t*)(ws + OFF_S1);
    uint32_t* s2p = (uint32_t*)(ws + OFF_S2);
    uint32_t* s3p = (uint32_t*)(ws + OFF_S3);
    uint32_t* s4p = (uint32_t*)(ws + OFF_S4);
    float*    s5  = (float*)(ws + OFF_S5);

    // SP0: pool4 (t-major z) + scan -> u32 planes
    k_pool4<<<4800, 256, 0, stream>>>(s_in, Z);
    k_scan_l0<<<64, 256, 0, stream>>>(Z, s0p, 16384);

    // SC1: conv 5x5 (2->16), all-o-in-regs -> z planes; scan -> s1p
    k_conv1<<<2400, 256, 0, stream>>>(s0p, W1, (float4*)Z);
    k_scan_plane<<<512, 256, 0, stream>>>((const float4*)Z, s1p, 131072);

    // SP1: fused pool2+scan (32x32 -> 16x16, 128 bc)
    k_pool2s<16, 131072, 32768><<<128, 256, 0, stream>>>(s1p, s2p);

    // SC2: conv 3x3 (16->32), 16-o halves -> z planes; scan -> s3p
    k_conv2<<<1200, 256, 0, stream>>>(s2p, W2, (float4*)Z);
    k_scan_plane<<<256, 256, 0, stream>>>((const float4*)Z, s3p, 65536);

    // SP2: fused pool2+scan (16x16 -> 8x8, 256 bc)
    k_pool2s<8, 65536, 16384><<<64, 256, 0, stream>>>(s3p, s4p);

    // SF1: tiled GEMM 2048->512 (A from planes) -> t-major z; scan -> s5
    k_fc1_gemm<<<dim3(10, 4, 8), 256, 0, stream>>>(s4p, Wf1, Z);
    k_scan_f32<<<16, 256, 0, stream>>>(Z, s5, 4096, 300);

    // SF2: FC 512->11 + final scan into d_out
    k_fc2<<<26, 256, 0, stream>>>(s5, Wf2, Z);
    k_scan_f32<<<1, 128, 0, stream>>>(Z, out, 88, 300);
}